// Round 4
// baseline (817.024 us; speedup 1.0000x reference)
//
#include <hip/hip_runtime.h>

typedef unsigned int u32;
typedef unsigned short u16;
typedef unsigned long long u64;
typedef long i64;
typedef float f32x4 __attribute__((ext_vector_type(4)));
typedef u32 u32x4 __attribute__((ext_vector_type(4)));
typedef _Float16 hf2 __attribute__((ext_vector_type(2)));

__device__ __forceinline__ u16 f2bf_rne(float f) {
    return __builtin_bit_cast(u16, (__bf16)f);
}
__device__ __forceinline__ float bf2f(u16 h) {
    return __builtin_bit_cast(float, ((u32)h) << 16);
}
__device__ __forceinline__ u32 pkh(float lo, float hi) { // pack 2xf16 (RTZ)
    return __builtin_bit_cast(u32, __builtin_amdgcn_cvt_pkrtz(lo, hi));
}
__device__ __forceinline__ hf2 ash(u32 v) { return __builtin_bit_cast(hf2, v); }
__device__ __forceinline__ float gelu_fast(float v) {
    float t = __builtin_amdgcn_exp2f(v * -2.4554673f);
    return v * __builtin_amdgcn_rcpf(1.f + t);
}
__device__ __forceinline__ i64 mk64(u32 lo, u32 hi) {
    return (i64)(((u64)hi << 32) | (u64)lo);
}

// ---------------------------------------------------------------------------
// K0: prep. w1f8[n=384][c=96] = fp8(lng[c]*w1[c][n]);  w2f8[c=96][n=384] = fp8(w2[n][c]);
//     B1s[n] = b1[n] + sum_c lnb[c]*w1[c][n];  wdup[c][343] = f16x2(w,w) conv weights.
// ---------------------------------------------------------------------------
__global__ void prep_weights(const float* __restrict__ w1, const float* __restrict__ w2,
                             const float* __restrict__ dww, const float* __restrict__ lng,
                             const float* __restrict__ lnb, const float* __restrict__ b1,
                             unsigned char* __restrict__ w1f8, unsigned char* __restrict__ w2f8,
                             float* __restrict__ B1s, u32* __restrict__ wdup) {
    int i = blockIdx.x * 256 + threadIdx.x;
    if (i < 18432) {                              // w1f8 pairs
        int n = i / 48, cp = i - n * 48;
        float a = lng[2 * cp] * w1[(2 * cp) * 384 + n];
        float b = lng[2 * cp + 1] * w1[(2 * cp + 1) * 384 + n];
        u32 w = (u32)__builtin_amdgcn_cvt_pk_fp8_f32(a, b, 0, false);
        *(u16*)(w1f8 + n * 96 + 2 * cp) = (u16)w;
    } else if (i < 36864) {                       // w2f8 pairs
        int i2 = i - 18432;
        int c = i2 / 192, np = i2 - c * 192;
        float a = w2[(2 * np) * 96 + c];
        float b = w2[(2 * np + 1) * 96 + c];
        u32 w = (u32)__builtin_amdgcn_cvt_pk_fp8_f32(a, b, 0, false);
        *(u16*)(w2f8 + c * 384 + 2 * np) = (u16)w;
    } else if (i < 37248) {                       // B1s
        int n = i - 36864;
        float s = b1[n];
        for (int c = 0; c < 96; ++c) s += lnb[c] * w1[c * 384 + n];
        B1s[n] = s;
    } else if (i < 70176) {                       // duplicated f16 conv weights
        int j = i - 37248;                        // j = c*343 + t
        float w = dww[j];
        wdup[j] = pkh(w, w);
    }
}

// ---------------------------------------------------------------------------
// K1-A: depthwise conv, fp32 v_fma_f32 on bf16-packed pairs (dirty-hi unpack).
// Block 256 = tz(4 d) x ty(8 h-pairs) x tx(8 w-groups). Tile 10x11x72 u32 pairs.
// ---------------------------------------------------------------------------
template<int PACKED>
__global__ __launch_bounds__(256, 5) void dwconvA(const float* __restrict__ x,
                                                  const float* __restrict__ dww,
                                                  const float* __restrict__ dwb,
                                                  u32* cw, u16* o16, int b_base) {
    __shared__ u32 tile32[7920];                  // 10 * 792
    const int tid = threadIdx.x;
    const int bx = blockIdx.x, c = blockIdx.y, b = b_base + blockIdx.z;
    const int d0 = (bx >> 2) * 4, h0 = (bx & 3) * 16;
    const float* xc = x + ((size_t)(b * 96 + c)) * 262144;

    for (int i = tid; i < 7700; i += 256) {
        int pz = i / 770;
        int rem = i - pz * 770;
        int r2 = rem / 70;
        int col = rem - r2 * 70;
        int d = d0 + pz - 3, h = h0 + 2 * r2 - 3, w = col - 3;
        float lo = 0.f, hi = 0.f;
        if (((unsigned)d < 64u) && ((unsigned)w < 64u)) {
            int base = d * 4096 + h * 64 + w;
            if ((unsigned)h < 64u) lo = xc[base];
            if ((unsigned)(h + 1) < 64u) hi = xc[base + 64];
        }
        int a = pz * 792 + r2 * 72 + col;
        int aw = ((((a >> 2) ^ ((a >> 5) & 1)) << 2)) | (a & 3);
        tile32[aw] = (u32)f2bf_rne(lo) | ((u32)f2bf_rne(hi) << 16);
    }
    __syncthreads();

    const int tx = tid & 7, ty = (tid >> 3) & 7, tz = tid >> 6;
    float a0[8], a1[8];
#pragma unroll
    for (int i = 0; i < 8; ++i) { a0[i] = 0.f; a1[i] = 0.f; }

    for (int kd = 0; kd < 7; ++kd) {
        const float* Wk = dww + c * 343 + kd * 49;    // uniform -> s_load
        const int pz = tz + kd;
#pragma unroll
        for (int pr = 0; pr < 4; ++pr) {
            const int g0 = pz * 198 + (ty + pr) * 18 + (tx << 1);
            u32 rb[16];
#pragma unroll
            for (int k = 0; k < 4; ++k) {
                int g = g0 + k;
                int ga = (g ^ ((g >> 3) & 1)) << 2;
                *(u32x4*)&rb[4 * k] = *(const u32x4*)(tile32 + ga);
            }
            float rlo[16], rhi[16];
#pragma unroll
            for (int t = 0; t < 16; ++t) {
                rlo[t] = __builtin_bit_cast(float, rb[t] << 16);   // exact bf16
                rhi[t] = __builtin_bit_cast(float, rb[t]);          // dirty low bits ~2^-8
            }
#pragma unroll
            for (int kw = 0; kw < 7; ++kw) {
                float wA = Wk[2 * pr * 7 + kw];       // a0<-lo and a1<-hi share
#pragma unroll
                for (int i = 0; i < 8; ++i) {
                    a0[i] = fmaf(rlo[kw + i], wA, a0[i]);
                    a1[i] = fmaf(rhi[kw + i], wA, a1[i]);
                }
                if (pr < 3) {
                    float wB = Wk[(2 * pr + 1) * 7 + kw];
#pragma unroll
                    for (int i = 0; i < 8; ++i) a0[i] = fmaf(rhi[kw + i], wB, a0[i]);
                }
                if (pr > 0) {
                    float wC = Wk[(2 * pr - 1) * 7 + kw];
#pragma unroll
                    for (int i = 0; i < 8; ++i) a1[i] = fmaf(rlo[kw + i], wC, a1[i]);
                }
            }
        }
    }

    const float bias = dwb[c];
    const int d = d0 + tz;
    const int hA = h0 + 2 * ty;
    if (PACKED == 0) {
        const int p = b * 262144 + d * 4096 + hA * 64 + 8 * tx;
        u32* dst = cw + c * 262144 + (p >> 1);
#pragma unroll
        for (int k = 0; k < 4; ++k)
            dst[k] = (u32)f2bf_rne(a0[2 * k] + bias) | ((u32)f2bf_rne(a0[2 * k + 1] + bias) << 16);
        u32* dst1 = dst + 32;
#pragma unroll
        for (int k = 0; k < 4; ++k)
            dst1[k] = (u32)f2bf_rne(a1[2 * k] + bias) | ((u32)f2bf_rne(a1[2 * k + 1] + bias) << 16);
    } else {
        size_t e = ((size_t)(b * 96 + c)) * 262144 + d * 4096 + hA * 64 + 8 * tx;
#pragma unroll
        for (int i = 0; i < 8; ++i) o16[2 * (e + i) + 1] = f2bf_rne(a0[i] + bias);
#pragma unroll
        for (int i = 0; i < 8; ++i) o16[2 * (e + 64 + i) + 1] = f2bf_rne(a1[i] + bias);
    }
}

// ---------------------------------------------------------------------------
// K1-B: depthwise conv via v_pk_fma_f16 — packed (h,h+1) accumulators, f16 LDS
// pairs, odd-kh operand via v_perm_b32, duplicated f16x2 weights (SGPR).
// Rate experiment vs variant A (batch 1 vs batch 0).
// ---------------------------------------------------------------------------
template<int PACKED>
__global__ __launch_bounds__(256, 5) void dwconvB(const float* __restrict__ x,
                                                  const float* __restrict__ dwb,
                                                  const u32* __restrict__ wdup,
                                                  u32* cw, u16* o16, int b_base) {
    __shared__ u32 tile32[7920];
    const int tid = threadIdx.x;
    const int bx = blockIdx.x, c = blockIdx.y, b = b_base + blockIdx.z;
    const int d0 = (bx >> 2) * 4, h0 = (bx & 3) * 16;
    const float* xc = x + ((size_t)(b * 96 + c)) * 262144;

    for (int i = tid; i < 7700; i += 256) {
        int pz = i / 770;
        int rem = i - pz * 770;
        int r2 = rem / 70;
        int col = rem - r2 * 70;
        int d = d0 + pz - 3, h = h0 + 2 * r2 - 3, w = col - 3;
        float lo = 0.f, hi = 0.f;
        if (((unsigned)d < 64u) && ((unsigned)w < 64u)) {
            int base = d * 4096 + h * 64 + w;
            if ((unsigned)h < 64u) lo = xc[base];
            if ((unsigned)(h + 1) < 64u) hi = xc[base + 64];
        }
        int a = pz * 792 + r2 * 72 + col;
        int aw = ((((a >> 2) ^ ((a >> 5) & 1)) << 2)) | (a & 3);
        tile32[aw] = pkh(lo, hi);
    }
    __syncthreads();

    const int tx = tid & 7, ty = (tid >> 3) & 7, tz = tid >> 6;
    hf2 acc[8];
#pragma unroll
    for (int i = 0; i < 8; ++i) acc[i] = hf2{0.f, 0.f};

    for (int kd = 0; kd < 7; ++kd) {
        const u32* wd = wdup + c * 343 + kd * 49;     // uniform -> s_load
        const int pz = tz + kd;
        u32 rbP[16];
#pragma unroll
        for (int pr = 0; pr < 4; ++pr) {
            const int g0 = pz * 198 + (ty + pr) * 18 + (tx << 1);
            u32 rbC[16];
#pragma unroll
            for (int k = 0; k < 4; ++k) {
                int g = g0 + k;
                int ga = (g ^ ((g >> 3) & 1)) << 2;
                *(u32x4*)&rbC[4 * k] = *(const u32x4*)(tile32 + ga);
            }
            // odd tap kh = 2pr-1: op = (hi of prev pair, lo of cur pair)
            if (pr > 0) {
                u32 pm[16];
#pragma unroll
                for (int t = 0; t < 16; ++t)
                    pm[t] = __builtin_amdgcn_perm(rbP[t], rbC[t], 0x01000706u);
#pragma unroll
                for (int kw = 0; kw < 7; ++kw) {
                    hf2 w = ash(wd[(2 * pr - 1) * 7 + kw]);
#pragma unroll
                    for (int i = 0; i < 8; ++i)
                        acc[i] = ash(pm[kw + i]) * w + acc[i];
                }
            }
            // even tap kh = 2pr: op = aligned current pair
#pragma unroll
            for (int kw = 0; kw < 7; ++kw) {
                hf2 w = ash(wd[2 * pr * 7 + kw]);
#pragma unroll
                for (int i = 0; i < 8; ++i)
                    acc[i] = ash(rbC[kw + i]) * w + acc[i];
            }
#pragma unroll
            for (int t = 0; t < 16; ++t) rbP[t] = rbC[t];
        }
    }

    const float bias = dwb[c];
    float a0[8], a1[8];
#pragma unroll
    for (int i = 0; i < 8; ++i) { a0[i] = (float)acc[i][0] + bias; a1[i] = (float)acc[i][1] + bias; }

    const int d = d0 + tz;
    const int hA = h0 + 2 * ty;
    if (PACKED == 0) {
        const int p = b * 262144 + d * 4096 + hA * 64 + 8 * tx;
        u32* dst = cw + c * 262144 + (p >> 1);
#pragma unroll
        for (int k = 0; k < 4; ++k)
            dst[k] = (u32)f2bf_rne(a0[2 * k]) | ((u32)f2bf_rne(a0[2 * k + 1]) << 16);
        u32* dst1 = dst + 32;
#pragma unroll
        for (int k = 0; k < 4; ++k)
            dst1[k] = (u32)f2bf_rne(a1[2 * k]) | ((u32)f2bf_rne(a1[2 * k + 1]) << 16);
    } else {
        size_t e = ((size_t)(b * 96 + c)) * 262144 + d * 4096 + hA * 64 + 8 * tx;
#pragma unroll
        for (int i = 0; i < 8; ++i) o16[2 * (e + i) + 1] = f2bf_rne(a0[i]);
#pragma unroll
        for (int i = 0; i < 8; ++i) o16[2 * (e + 64 + i) + 1] = f2bf_rne(a1[i]);
    }
}

// ---------------------------------------------------------------------------
// K2: LN folded into fp8 GEMMs; one barrier; wave owns 16 positions.
// 512 threads (8 waves), 51.5 KB LDS -> 3 blocks/CU (75% occupancy).
// ---------------------------------------------------------------------------
template<int CWP, int WF>
__global__ __launch_bounds__(512) void mlp2(const void* cwsrc,
                                            const unsigned char* __restrict__ w1f8,
                                            const unsigned char* __restrict__ w2f8,
                                            const float* __restrict__ B1sg,
                                            const float* __restrict__ w1f,
                                            const float* __restrict__ w2f,
                                            const float* __restrict__ lng,
                                            const float* __restrict__ lnb,
                                            const float* __restrict__ b1g,
                                            const float* __restrict__ b2g,
                                            const float* __restrict__ gam,
                                            const float* __restrict__ x,
                                            float* __restrict__ out) {
    __shared__ __align__(16) unsigned char W1[39936];   // [384 n][stride 104 B] fp8
    __shared__ float B1s[384];
    __shared__ float MISC[192];                         // b2[96] | gamma[96]
    __shared__ __align__(16) unsigned char HS[8][1152]; // per-wave [16 pos][stride 72 B]

    const int tid = threadIdx.x;

    if (WF == 0) {
        for (int i = tid; i < 9216; i += 512) {
            int n = i / 24, q = i - n * 24;
            *(u32*)&W1[n * 104 + q * 4] = ((const u32*)w1f8)[i];
        }
        if (tid < 384) B1s[tid] = B1sg[tid];
    } else {
        for (int i = tid; i < 18432; i += 512) {
            int n = i / 48, cp = i - n * 48;
            float a = lng[2 * cp] * w1f[(2 * cp) * 384 + n];
            float b = lng[2 * cp + 1] * w1f[(2 * cp + 1) * 384 + n];
            u32 w = (u32)__builtin_amdgcn_cvt_pk_fp8_f32(a, b, 0, false);
            *(u16*)&W1[n * 104 + 2 * cp] = (u16)w;
        }
        if (tid < 384) {
            float s = b1g[tid];
            for (int c = 0; c < 96; ++c) s += lnb[c] * w1f[c * 384 + tid];
            B1s[tid] = s;
        }
    }
    if (tid < 192) MISC[tid] = (tid < 96) ? b2g[tid] : gam[tid - 96];
    __syncthreads();

    const int wv = tid >> 6, lane = tid & 63;
    const int p = lane & 15, G = lane >> 4;
    const int p0 = blockIdx.x * 128 + wv * 16;          // global flat position base
    const int b = p0 >> 18, prel = p0 & 262143;
    unsigned char* hsw = &HS[wv][0];

    // ---- load conv values in A-frag layout: c = kk*32 + G*8 + j, pos = p0 + p
    float v[3][8];
    if (CWP == 0) {
        const u16* cw16 = (const u16*)cwsrc;
#pragma unroll
        for (int kk = 0; kk < 3; ++kk)
#pragma unroll
            for (int j = 0; j < 8; ++j) {
                int c = kk * 32 + G * 8 + j;
                v[kk][j] = bf2f(cw16[(size_t)c * 524288 + p0 + p]);
            }
    } else {
        const u32* ow = (const u32*)cwsrc;
#pragma unroll
        for (int kk = 0; kk < 3; ++kk)
#pragma unroll
            for (int j = 0; j < 8; ++j) {
                int c = kk * 32 + G * 8 + j;
                v[kk][j] = bf2f((u16)(ow[((size_t)(b * 96 + c)) * 262144 + prel + p] >> 16));
            }
    }

    // ---- LN stats across the 4 G-lanes sharing this position
    float s = 0.f, sq = 0.f;
#pragma unroll
    for (int kk = 0; kk < 3; ++kk)
#pragma unroll
        for (int j = 0; j < 8; ++j) { s += v[kk][j]; sq += v[kk][j] * v[kk][j]; }
    s += __shfl_xor(s, 16); sq += __shfl_xor(sq, 16);
    s += __shfl_xor(s, 32); sq += __shfl_xor(sq, 32);
    float mu = s * (1.f / 96.f);
    float rstd = rsqrtf(sq * (1.f / 96.f) - mu * mu + 1e-5f);

    // ---- fp8 A-fragments (normalized; gamma/beta folded into W1/B1s)
    i64 aF[3];
#pragma unroll
    for (int kk = 0; kk < 3; ++kk) {
        u32 lo = 0, hi = 0;
        float n0 = (v[kk][0] - mu) * rstd, n1 = (v[kk][1] - mu) * rstd;
        float n2 = (v[kk][2] - mu) * rstd, n3 = (v[kk][3] - mu) * rstd;
        float n4 = (v[kk][4] - mu) * rstd, n5 = (v[kk][5] - mu) * rstd;
        float n6 = (v[kk][6] - mu) * rstd, n7 = (v[kk][7] - mu) * rstd;
        lo = (u32)__builtin_amdgcn_cvt_pk_fp8_f32(n0, n1, (int)lo, false);
        lo = (u32)__builtin_amdgcn_cvt_pk_fp8_f32(n2, n3, (int)lo, true);
        hi = (u32)__builtin_amdgcn_cvt_pk_fp8_f32(n4, n5, (int)hi, false);
        hi = (u32)__builtin_amdgcn_cvt_pk_fp8_f32(n6, n7, (int)hi, true);
        aF[kk] = mk64(lo, hi);
    }

    f32x4 acc[6];
#pragma unroll
    for (int i = 0; i < 6; ++i) acc[i] = f32x4{0.f, 0.f, 0.f, 0.f};

    for (int j = 0; j < 6; ++j) {
        // GEMM1 (swapped): D[n][pos] — lane keeps its own position's outputs
        f32x4 c1[4];
#pragma unroll
        for (int nt = 0; nt < 4; ++nt) {
            int n16 = j * 4 + nt;
            c1[nt] = f32x4{0.f, 0.f, 0.f, 0.f};
#pragma unroll
            for (int kk = 0; kk < 3; ++kk) {
                i64 wfrag = *(const i64*)&W1[(n16 * 16 + p) * 104 + kk * 32 + G * 8];
                c1[nt] = __builtin_amdgcn_mfma_f32_16x16x32_fp8_fp8(wfrag, aF[kk], c1[nt], 0, 0, 0);
            }
        }
        // bias (LN-folded) + GELU -> fp8 -> per-wave LDS scratch
#pragma unroll
        for (int nt = 0; nt < 4; ++nt) {
            f32x4 bb = *(const f32x4*)&B1s[(j * 4 + nt) * 16 + 4 * G];
            float g0 = gelu_fast(c1[nt][0] + bb[0]);
            float g1 = gelu_fast(c1[nt][1] + bb[1]);
            float g2 = gelu_fast(c1[nt][2] + bb[2]);
            float g3 = gelu_fast(c1[nt][3] + bb[3]);
            u32 w = 0;
            w = (u32)__builtin_amdgcn_cvt_pk_fp8_f32(g0, g1, (int)w, false);
            w = (u32)__builtin_amdgcn_cvt_pk_fp8_f32(g2, g3, (int)w, true);
            *(u32*)&hsw[p * 72 + nt * 16 + 4 * G] = w;
        }
        asm volatile("s_waitcnt lgkmcnt(0)" ::: "memory");
        __builtin_amdgcn_sched_barrier(0);

        i64 hF[2];
#pragma unroll
        for (int kkj = 0; kkj < 2; ++kkj)
            hF[kkj] = *(const i64*)&hsw[p * 72 + kkj * 32 + G * 8];

        // GEMM2: D[pos][c], accumulate over n
#pragma unroll
        for (int ct = 0; ct < 6; ++ct) {
#pragma unroll
            for (int kkj = 0; kkj < 2; ++kkj) {
                i64 w2frag;
                if (WF == 0) {
                    w2frag = *(const i64*)&w2f8[(size_t)(ct * 16 + p) * 384 + (j * 2 + kkj) * 32 + G * 8];
                } else {
                    int c = ct * 16 + p;
                    int nb = (j * 2 + kkj) * 32 + G * 8;
                    u32 lo = 0, hi = 0;
                    lo = (u32)__builtin_amdgcn_cvt_pk_fp8_f32(w2f[(nb + 0) * 96 + c], w2f[(nb + 1) * 96 + c], (int)lo, false);
                    lo = (u32)__builtin_amdgcn_cvt_pk_fp8_f32(w2f[(nb + 2) * 96 + c], w2f[(nb + 3) * 96 + c], (int)lo, true);
                    hi = (u32)__builtin_amdgcn_cvt_pk_fp8_f32(w2f[(nb + 4) * 96 + c], w2f[(nb + 5) * 96 + c], (int)hi, false);
                    hi = (u32)__builtin_amdgcn_cvt_pk_fp8_f32(w2f[(nb + 6) * 96 + c], w2f[(nb + 7) * 96 + c], (int)hi, true);
                    w2frag = mk64(lo, hi);
                }
                acc[ct] = __builtin_amdgcn_mfma_f32_16x16x32_fp8_fp8(hF[kkj], w2frag, acc[ct], 0, 0, 0);
            }
        }
    }

    // ---- epilogue: bias2 + gamma + residual, vectorized f32x4
#pragma unroll
    for (int ct = 0; ct < 6; ++ct) {
        int c = ct * 16 + p;
        size_t xi = ((size_t)(b * 96 + c)) * 262144 + prel + G * 4;
        f32x4 xv = *(const f32x4*)&x[xi];
        float b2c = MISC[c], gc = MISC[96 + c];
        f32x4 o;
#pragma unroll
        for (int r = 0; r < 4; ++r) o[r] = (acc[ct][r] + b2c) * gc + xv[r];
        *(f32x4*)&out[xi] = o;
    }
}

// ---------------------------------------------------------------------------
extern "C" void kernel_launch(void* const* d_in, const int* in_sizes, int n_in,
                              void* d_out, int out_size, void* d_ws, size_t ws_size,
                              hipStream_t stream) {
    const float* x   = (const float*)d_in[0];
    const float* dww = (const float*)d_in[1];
    const float* dwb = (const float*)d_in[2];
    const float* lng = (const float*)d_in[3];
    const float* lnb = (const float*)d_in[4];
    const float* w1  = (const float*)d_in[5];
    const float* b1  = (const float*)d_in[6];
    const float* w2  = (const float*)d_in[7];
    const float* b2  = (const float*)d_in[8];
    const float* gam = (const float*)d_in[9];
    float* out = (float*)d_out;

    // ws: w1f8 @0 (36864) | w2f8 @36864 (36864) | B1s @73728 (1536)
    //     | wdup @75264 (131712) | cw @206976 (100663296)
    const size_t NEED_W = 206976;
    const size_t NEED_FULL = NEED_W + 100663296ull;
    const bool wsW = ws_size >= NEED_W;
    const bool wsCW = ws_size >= NEED_FULL;

    unsigned char* w1f8 = (unsigned char*)d_ws;
    unsigned char* w2f8 = (unsigned char*)d_ws + 36864;
    float* B1s = (float*)((char*)d_ws + 73728);
    u32* wdup = (u32*)((char*)d_ws + 75264);
    u32* cw = (u32*)((char*)d_ws + 206976);

    if (wsW)
        hipLaunchKernelGGL(prep_weights, dim3(275), dim3(256), 0, stream,
                           w1, w2, dww, lng, lnb, b1, w1f8, w2f8, B1s, wdup);

    dim3 g1(64, 96, 1), blk(256);
    if (wsCW) {
        // A/B rate experiment: batch 0 -> fp32 fma, batch 1 -> pk_fma_f16
        hipLaunchKernelGGL((dwconvA<0>), g1, blk, 0, stream, x, dww, dwb, cw, (u16*)d_out, 0);
        hipLaunchKernelGGL((dwconvB<0>), g1, blk, 0, stream, x, dwb, wdup, cw, (u16*)d_out, 1);
    } else if (wsW) {
        hipLaunchKernelGGL((dwconvA<1>), g1, blk, 0, stream, x, dww, dwb, cw, (u16*)d_out, 0);
        hipLaunchKernelGGL((dwconvB<1>), g1, blk, 0, stream, x, dwb, wdup, cw, (u16*)d_out, 1);
    } else {
        dim3 g1b(64, 96, 2);
        hipLaunchKernelGGL((dwconvA<1>), g1b, blk, 0, stream, x, dww, dwb, cw, (u16*)d_out, 0);
    }

    dim3 g2(4096), blk2(512);
    if (wsCW)
        hipLaunchKernelGGL((mlp2<0, 0>), g2, blk2, 0, stream, (const void*)cw,
                           w1f8, w2f8, B1s, w1, w2, lng, lnb, b1, b2, gam, x, out);
    else if (wsW)
        hipLaunchKernelGGL((mlp2<1, 0>), g2, blk2, 0, stream, (const void*)d_out,
                           w1f8, w2f8, B1s, w1, w2, lng, lnb, b1, b2, gam, x, out);
    else
        hipLaunchKernelGGL((mlp2<1, 1>), g2, blk2, 0, stream, (const void*)d_out,
                           w1f8, w2f8, B1s, w1, w2, lng, lnb, b1, b2, gam, x, out);
}

// Round 5
// 709.709 us; speedup vs baseline: 1.1512x; 1.1512x over previous
//
#include <hip/hip_runtime.h>

typedef unsigned int u32;
typedef unsigned short u16;
typedef unsigned long long u64;
typedef long i64;
typedef float f32x4 __attribute__((ext_vector_type(4)));
typedef u32 u32x4 __attribute__((ext_vector_type(4)));

__device__ __forceinline__ u16 f2bf_rne(float f) {
    return __builtin_bit_cast(u16, (__bf16)f);
}
__device__ __forceinline__ float bf2f(u16 h) {
    return __builtin_bit_cast(float, ((u32)h) << 16);
}
__device__ __forceinline__ float gelu_fast(float v) {
    float t = __builtin_amdgcn_exp2f(v * -2.4554673f);
    return v * __builtin_amdgcn_rcpf(1.f + t);
}
__device__ __forceinline__ i64 mk64(u32 lo, u32 hi) {
    return (i64)(((u64)hi << 32) | (u64)lo);
}
__device__ __forceinline__ u32 pk4(float a, float b, float c, float d) {
    u32 w = (u32)__builtin_amdgcn_cvt_pk_fp8_f32(a, b, 0, false);
    return (u32)__builtin_amdgcn_cvt_pk_fp8_f32(c, d, (int)w, true);
}

// ---------------------------------------------------------------------------
// K0: prep — weights in MFMA-fragment order.
// W1L[(j16*3+kk)*64+lane] : 8B = fp8(lng[c]*w1[c][n]), n=j16*16+(lane&15),
//                           c=kk*32+(lane>>4)*8+m   (GEMM1 A-operand frags)
// W2L[(ct*12+jk)*64+lane] : 8B = fp8(w2[n][c]), c=ct*16+(lane&15),
//                           n=jk*32+(lane>>4)*8+m   (GEMM2 B-operand frags)
// B1s[n] = b1[n] + sum_c lnb[c]*w1[c][n]            (LN beta folded)
// ---------------------------------------------------------------------------
__global__ void prep_weights(const float* __restrict__ w1, const float* __restrict__ w2,
                             const float* __restrict__ lng, const float* __restrict__ lnb,
                             const float* __restrict__ b1,
                             i64* __restrict__ W1L, i64* __restrict__ W2L,
                             float* __restrict__ B1s) {
    int i = blockIdx.x * 256 + threadIdx.x;
    if (i < 4608) {                               // W1L: 24 j16 * 3 kk * 64 lanes
        int n16 = i / 192, r = i - n16 * 192;
        int kk = r >> 6, lane = r & 63;
        int n = n16 * 16 + (lane & 15);
        int cb = kk * 32 + (lane >> 4) * 8;
        float s0 = lng[cb + 0] * w1[(cb + 0) * 384 + n];
        float s1 = lng[cb + 1] * w1[(cb + 1) * 384 + n];
        float s2 = lng[cb + 2] * w1[(cb + 2) * 384 + n];
        float s3 = lng[cb + 3] * w1[(cb + 3) * 384 + n];
        float s4 = lng[cb + 4] * w1[(cb + 4) * 384 + n];
        float s5 = lng[cb + 5] * w1[(cb + 5) * 384 + n];
        float s6 = lng[cb + 6] * w1[(cb + 6) * 384 + n];
        float s7 = lng[cb + 7] * w1[(cb + 7) * 384 + n];
        W1L[i] = mk64(pk4(s0, s1, s2, s3), pk4(s4, s5, s6, s7));
    } else if (i < 9216) {                        // W2L: 6 ct * 12 jk * 64 lanes
        int e = i - 4608;
        int r = e & 767, lane = r & 63, jk = r >> 6;
        int c = ((e / 768) * 16) + (lane & 15);
        int nb = jk * 32 + (lane >> 4) * 8;
        float s0 = w2[(nb + 0) * 96 + c], s1 = w2[(nb + 1) * 96 + c];
        float s2 = w2[(nb + 2) * 96 + c], s3 = w2[(nb + 3) * 96 + c];
        float s4 = w2[(nb + 4) * 96 + c], s5 = w2[(nb + 5) * 96 + c];
        float s6 = w2[(nb + 6) * 96 + c], s7 = w2[(nb + 7) * 96 + c];
        W2L[e] = mk64(pk4(s0, s1, s2, s3), pk4(s4, s5, s6, s7));
    } else if (i < 9600) {                        // B1s
        int n = i - 9216;
        float s = b1[n];
        for (int c = 0; c < 96; ++c) s += lnb[c] * w1[c * 384 + n];
        B1s[n] = s;
    }
}

// ---------------------------------------------------------------------------
// K1: depthwise 7x7x7 conv + bias, fp32 v_fma on bf16-packed (h,h+1) pairs.
// Block 256 = tz(4 d) x ty(8 h-pairs) x tx(8 w-groups). Tile 10x11x72 u32.
// ---------------------------------------------------------------------------
template<int PACKED>
__global__ __launch_bounds__(256, 5) void dwconvA(const float* __restrict__ x,
                                                  const float* __restrict__ dww,
                                                  const float* __restrict__ dwb,
                                                  u32* cw, u16* o16) {
    __shared__ u32 tile32[7920];                  // 10 * 792
    const int tid = threadIdx.x;
    const int bx = blockIdx.x, c = blockIdx.y, b = blockIdx.z;
    const int d0 = (bx >> 2) * 4, h0 = (bx & 3) * 16;
    const float* xc = x + ((size_t)(b * 96 + c)) * 262144;

    for (int i = tid; i < 7700; i += 256) {
        int pz = i / 770;
        int rem = i - pz * 770;
        int r2 = rem / 70;
        int col = rem - r2 * 70;
        int d = d0 + pz - 3, h = h0 + 2 * r2 - 3, w = col - 3;
        float lo = 0.f, hi = 0.f;
        if (((unsigned)d < 64u) && ((unsigned)w < 64u)) {
            int base = d * 4096 + h * 64 + w;
            if ((unsigned)h < 64u) lo = xc[base];
            if ((unsigned)(h + 1) < 64u) hi = xc[base + 64];
        }
        int a = pz * 792 + r2 * 72 + col;
        int aw = ((((a >> 2) ^ ((a >> 5) & 1)) << 2)) | (a & 3);
        tile32[aw] = (u32)f2bf_rne(lo) | ((u32)f2bf_rne(hi) << 16);
    }
    __syncthreads();

    const int tx = tid & 7, ty = (tid >> 3) & 7, tz = tid >> 6;
    float a0[8], a1[8];
#pragma unroll
    for (int i = 0; i < 8; ++i) { a0[i] = 0.f; a1[i] = 0.f; }

    for (int kd = 0; kd < 7; ++kd) {
        const float* Wk = dww + c * 343 + kd * 49;    // uniform -> s_load
        const int pz = tz + kd;
#pragma unroll
        for (int pr = 0; pr < 4; ++pr) {
            const int g0 = pz * 198 + (ty + pr) * 18 + (tx << 1);
            u32 rb[16];
#pragma unroll
            for (int k = 0; k < 4; ++k) {
                int g = g0 + k;
                int ga = (g ^ ((g >> 3) & 1)) << 2;
                *(u32x4*)&rb[4 * k] = *(const u32x4*)(tile32 + ga);
            }
            float rlo[16], rhi[16];
#pragma unroll
            for (int t = 0; t < 16; ++t) {
                rlo[t] = __builtin_bit_cast(float, rb[t] << 16);    // exact bf16
                rhi[t] = __builtin_bit_cast(float, rb[t]);          // dirty low bits
            }
#pragma unroll
            for (int kw = 0; kw < 7; ++kw) {
                float wA = Wk[2 * pr * 7 + kw];
#pragma unroll
                for (int i = 0; i < 8; ++i) {
                    a0[i] = fmaf(rlo[kw + i], wA, a0[i]);
                    a1[i] = fmaf(rhi[kw + i], wA, a1[i]);
                }
                if (pr < 3) {
                    float wB = Wk[(2 * pr + 1) * 7 + kw];
#pragma unroll
                    for (int i = 0; i < 8; ++i) a0[i] = fmaf(rhi[kw + i], wB, a0[i]);
                }
                if (pr > 0) {
                    float wC = Wk[(2 * pr - 1) * 7 + kw];
#pragma unroll
                    for (int i = 0; i < 8; ++i) a1[i] = fmaf(rlo[kw + i], wC, a1[i]);
                }
            }
        }
    }

    const float bias = dwb[c];
    const int d = d0 + tz;
    const int hA = h0 + 2 * ty;
    if (PACKED == 0) {
        const int p = b * 262144 + d * 4096 + hA * 64 + 8 * tx;
        u32* dst = cw + c * 262144 + (p >> 1);
#pragma unroll
        for (int k = 0; k < 4; ++k)
            dst[k] = (u32)f2bf_rne(a0[2 * k] + bias) | ((u32)f2bf_rne(a0[2 * k + 1] + bias) << 16);
        u32* dst1 = dst + 32;
#pragma unroll
        for (int k = 0; k < 4; ++k)
            dst1[k] = (u32)f2bf_rne(a1[2 * k] + bias) | ((u32)f2bf_rne(a1[2 * k + 1] + bias) << 16);
    } else {
        size_t e = ((size_t)(b * 96 + c)) * 262144 + d * 4096 + hA * 64 + 8 * tx;
#pragma unroll
        for (int i = 0; i < 8; ++i) o16[2 * (e + i) + 1] = f2bf_rne(a0[i] + bias);
#pragma unroll
        for (int i = 0; i < 8; ++i) o16[2 * (e + 64 + i) + 1] = f2bf_rne(a1[i] + bias);
    }
}

// ---------------------------------------------------------------------------
// K2 v3: fully wave-independent LN+MLP. No __syncthreads. Weights loaded as
// pre-laid-out fragments (coalesced 512B/load, L1/L2 resident). 2 pos-tiles
// (32 positions) per wave. LDS = per-wave H scratch only (9 KB/block).
// CWP: 0 = conv-out bf16 in ws [c][524288]; 1 = hi bytes of d_out words.
// WF : 0 = fragment tables from ws; 1 = build frags from f32 (slow fallback).
// ---------------------------------------------------------------------------
template<int CWP, int WF>
__global__ __launch_bounds__(256, 4) void mlp3(const void* cwsrc,
                                               const i64* __restrict__ W1L,
                                               const i64* __restrict__ W2L,
                                               const float* __restrict__ B1s,
                                               const float* __restrict__ w1f,
                                               const float* __restrict__ w2f,
                                               const float* __restrict__ lng,
                                               const float* __restrict__ lnb,
                                               const float* __restrict__ b1g,
                                               const float* __restrict__ b2g,
                                               const float* __restrict__ gam,
                                               const float* __restrict__ x,
                                               float* __restrict__ out) {
    __shared__ __align__(16) unsigned char HS[4][2][1152];  // [wave][tile][16p * 72B]

    const int tid = threadIdx.x;
    const int wv = tid >> 6, lane = tid & 63;
    const int p = lane & 15, G = lane >> 4;
    const int pos0 = blockIdx.x * 128 + wv * 32;
    const int b = pos0 >> 18, prel0 = pos0 & 262143;
    unsigned char* hsw = &HS[wv][0][0];

    // ---- conv gather (A-frag layout) + LN + fp8 A-frags, per tile
    i64 aF[2][3];
#pragma unroll
    for (int t = 0; t < 2; ++t) {
        float v[3][8];
        if (CWP == 0) {
            const u16* cw16 = (const u16*)cwsrc;
#pragma unroll
            for (int kk = 0; kk < 3; ++kk)
#pragma unroll
                for (int m = 0; m < 8; ++m) {
                    int c = kk * 32 + G * 8 + m;
                    v[kk][m] = bf2f(cw16[(size_t)c * 524288 + pos0 + t * 16 + p]);
                }
        } else {
            const u32* ow = (const u32*)cwsrc;
#pragma unroll
            for (int kk = 0; kk < 3; ++kk)
#pragma unroll
                for (int m = 0; m < 8; ++m) {
                    int c = kk * 32 + G * 8 + m;
                    v[kk][m] = bf2f((u16)(ow[((size_t)(b * 96 + c)) * 262144 + prel0 + t * 16 + p] >> 16));
                }
        }
        float s = 0.f, sq = 0.f;
#pragma unroll
        for (int kk = 0; kk < 3; ++kk)
#pragma unroll
            for (int m = 0; m < 8; ++m) { s += v[kk][m]; sq += v[kk][m] * v[kk][m]; }
        s += __shfl_xor(s, 16); sq += __shfl_xor(sq, 16);
        s += __shfl_xor(s, 32); sq += __shfl_xor(sq, 32);
        float mu = s * (1.f / 96.f);
        float rstd = rsqrtf(sq * (1.f / 96.f) - mu * mu + 1e-5f);
#pragma unroll
        for (int kk = 0; kk < 3; ++kk) {
            float n0 = (v[kk][0] - mu) * rstd, n1 = (v[kk][1] - mu) * rstd;
            float n2 = (v[kk][2] - mu) * rstd, n3 = (v[kk][3] - mu) * rstd;
            float n4 = (v[kk][4] - mu) * rstd, n5 = (v[kk][5] - mu) * rstd;
            float n6 = (v[kk][6] - mu) * rstd, n7 = (v[kk][7] - mu) * rstd;
            aF[t][kk] = mk64(pk4(n0, n1, n2, n3), pk4(n4, n5, n6, n7));
        }
    }

    f32x4 acc[2][6];
#pragma unroll
    for (int t = 0; t < 2; ++t)
#pragma unroll
        for (int i = 0; i < 6; ++i) acc[t][i] = f32x4{0.f, 0.f, 0.f, 0.f};

    for (int j = 0; j < 6; ++j) {
        // ---- W1 fragments (coalesced dwordx2; shared by both tiles)
        i64 wf[12];
#pragma unroll
        for (int q = 0; q < 12; ++q) {            // q = nt*3 + kk
            if (WF == 0) {
                wf[q] = W1L[(j * 12 + q) * 64 + lane];
            } else {
                int nt = q / 3, kk = q - nt * 3;
                int n = (j * 4 + nt) * 16 + p;
                int cb = kk * 32 + G * 8;
                wf[q] = mk64(
                    pk4(lng[cb + 0] * w1f[(cb + 0) * 384 + n], lng[cb + 1] * w1f[(cb + 1) * 384 + n],
                        lng[cb + 2] * w1f[(cb + 2) * 384 + n], lng[cb + 3] * w1f[(cb + 3) * 384 + n]),
                    pk4(lng[cb + 4] * w1f[(cb + 4) * 384 + n], lng[cb + 5] * w1f[(cb + 5) * 384 + n],
                        lng[cb + 6] * w1f[(cb + 6) * 384 + n], lng[cb + 7] * w1f[(cb + 7) * 384 + n]));
            }
        }
        // ---- bias (LN-folded), shared across tiles
        f32x4 bb[4];
#pragma unroll
        for (int nt = 0; nt < 4; ++nt)
            bb[nt] = *(const f32x4*)&B1s[(j * 4 + nt) * 16 + 4 * G];

        // ---- GEMM1 + GELU + HS write, per tile
#pragma unroll
        for (int t = 0; t < 2; ++t) {
            f32x4 c1[4];
#pragma unroll
            for (int nt = 0; nt < 4; ++nt) {
                c1[nt] = f32x4{0.f, 0.f, 0.f, 0.f};
#pragma unroll
                for (int kk = 0; kk < 3; ++kk)
                    c1[nt] = __builtin_amdgcn_mfma_f32_16x16x32_fp8_fp8(wf[nt * 3 + kk], aF[t][kk], c1[nt], 0, 0, 0);
            }
#pragma unroll
            for (int nt = 0; nt < 4; ++nt) {
                float g0 = gelu_fast(c1[nt][0] + bb[nt][0]);
                float g1 = gelu_fast(c1[nt][1] + bb[nt][1]);
                float g2 = gelu_fast(c1[nt][2] + bb[nt][2]);
                float g3 = gelu_fast(c1[nt][3] + bb[nt][3]);
                *(u32*)&hsw[t * 1152 + p * 72 + nt * 16 + 4 * G] = pk4(g0, g1, g2, g3);
            }
        }

        // ---- W2 fragments issued BEFORE the LDS fence (vmcnt, not lgkm)
        i64 w2r[12];
#pragma unroll
        for (int q = 0; q < 12; ++q) {            // q = ct*2 + kkj
            if (WF == 0) {
                int ct = q >> 1, kkj = q & 1;
                w2r[q] = W2L[(ct * 12 + j * 2 + kkj) * 64 + lane];
            } else {
                int ct = q >> 1, kkj = q & 1;
                int c = ct * 16 + p;
                int nb = (j * 2 + kkj) * 32 + G * 8;
                w2r[q] = mk64(
                    pk4(w2f[(nb + 0) * 96 + c], w2f[(nb + 1) * 96 + c],
                        w2f[(nb + 2) * 96 + c], w2f[(nb + 3) * 96 + c]),
                    pk4(w2f[(nb + 4) * 96 + c], w2f[(nb + 5) * 96 + c],
                        w2f[(nb + 6) * 96 + c], w2f[(nb + 7) * 96 + c]));
            }
        }

        asm volatile("s_waitcnt lgkmcnt(0)" ::: "memory");
        __builtin_amdgcn_sched_barrier(0);

        i64 hF[2][2];
#pragma unroll
        for (int t = 0; t < 2; ++t)
#pragma unroll
            for (int kkj = 0; kkj < 2; ++kkj)
                hF[t][kkj] = *(const i64*)&hsw[t * 1152 + p * 72 + kkj * 32 + G * 8];

        // ---- GEMM2 accumulate
#pragma unroll
        for (int ct = 0; ct < 6; ++ct)
#pragma unroll
            for (int kkj = 0; kkj < 2; ++kkj) {
#pragma unroll
                for (int t = 0; t < 2; ++t)
                    acc[t][ct] = __builtin_amdgcn_mfma_f32_16x16x32_fp8_fp8(hF[t][kkj], w2r[ct * 2 + kkj], acc[t][ct], 0, 0, 0);
            }
    }

    // ---- epilogue: bias2 + gamma + residual (fp32, exact x)
#pragma unroll
    for (int ct = 0; ct < 6; ++ct) {
        int c = ct * 16 + p;
        float b2c = b2g[c], gc = gam[c];
#pragma unroll
        for (int t = 0; t < 2; ++t) {
            size_t xi = ((size_t)(b * 96 + c)) * 262144 + prel0 + t * 16 + G * 4;
            f32x4 xv = *(const f32x4*)&x[xi];
            f32x4 o;
#pragma unroll
            for (int r = 0; r < 4; ++r) o[r] = (acc[t][ct][r] + b2c) * gc + xv[r];
            *(f32x4*)&out[xi] = o;
        }
    }
}

// ---------------------------------------------------------------------------
extern "C" void kernel_launch(void* const* d_in, const int* in_sizes, int n_in,
                              void* d_out, int out_size, void* d_ws, size_t ws_size,
                              hipStream_t stream) {
    const float* x   = (const float*)d_in[0];
    const float* dww = (const float*)d_in[1];
    const float* dwb = (const float*)d_in[2];
    const float* lng = (const float*)d_in[3];
    const float* lnb = (const float*)d_in[4];
    const float* w1  = (const float*)d_in[5];
    const float* b1  = (const float*)d_in[6];
    const float* w2  = (const float*)d_in[7];
    const float* b2  = (const float*)d_in[8];
    const float* gam = (const float*)d_in[9];
    float* out = (float*)d_out;

    // ws: W1L @0 (36864) | W2L @36864 (36864) | B1s @73728 (1536) | cw @75264
    const size_t NEED_W = 75264;
    const size_t NEED_FULL = NEED_W + 100663296ull;
    const bool wsW = ws_size >= NEED_W;
    const bool wsCW = ws_size >= NEED_FULL;

    i64* W1L = (i64*)d_ws;
    i64* W2L = (i64*)((char*)d_ws + 36864);
    float* B1s = (float*)((char*)d_ws + 73728);
    u32* cw = (u32*)((char*)d_ws + 75264);

    if (wsW)
        hipLaunchKernelGGL(prep_weights, dim3(38), dim3(256), 0, stream,
                           w1, w2, lng, lnb, b1, W1L, W2L, B1s);

    dim3 g1(64, 96, 2), blk(256);
    if (wsCW)
        hipLaunchKernelGGL((dwconvA<0>), g1, blk, 0, stream, x, dww, dwb, cw, (u16*)d_out);
    else
        hipLaunchKernelGGL((dwconvA<1>), g1, blk, 0, stream, x, dww, dwb, cw, (u16*)d_out);

    dim3 g2(4096), blk2(256);
    if (wsCW)
        hipLaunchKernelGGL((mlp3<0, 0>), g2, blk2, 0, stream, (const void*)cw,
                           W1L, W2L, B1s, w1, w2, lng, lnb, b1, b2, gam, x, out);
    else if (wsW)
        hipLaunchKernelGGL((mlp3<1, 0>), g2, blk2, 0, stream, (const void*)d_out,
                           W1L, W2L, B1s, w1, w2, lng, lnb, b1, b2, gam, x, out);
    else
        hipLaunchKernelGGL((mlp3<1, 1>), g2, blk2, 0, stream, (const void*)d_out,
                           W1L, W2L, B1s, w1, w2, lng, lnb, b1, b2, gam, x, out);
}

// Round 6
// 474.862 us; speedup vs baseline: 1.7206x; 1.4946x over previous
//
#include <hip/hip_runtime.h>

typedef unsigned int u32;
typedef unsigned short u16;
typedef unsigned long long u64;
typedef long i64;
typedef float f32x4 __attribute__((ext_vector_type(4)));
typedef u32 u32x4 __attribute__((ext_vector_type(4)));

__device__ __forceinline__ u16 f2bf_rne(float f) {
    return __builtin_bit_cast(u16, (__bf16)f);
}
__device__ __forceinline__ float bf2f(u16 h) {
    return __builtin_bit_cast(float, ((u32)h) << 16);
}
__device__ __forceinline__ float gelu_fast(float v) {
    float t = __builtin_amdgcn_exp2f(v * -2.4554673f);
    return v * __builtin_amdgcn_rcpf(1.f + t);
}
__device__ __forceinline__ i64 mk64(u32 lo, u32 hi) {
    return (i64)(((u64)hi << 32) | (u64)lo);
}
__device__ __forceinline__ u32 pk4(float a, float b, float c, float d) {
    u32 w = (u32)__builtin_amdgcn_cvt_pk_fp8_f32(a, b, 0, false);
    return (u32)__builtin_amdgcn_cvt_pk_fp8_f32(c, d, (int)w, true);
}

// ---------------------------------------------------------------------------
// K0: prep — MLP weights in MFMA-fragment order (unchanged from R5).
// ---------------------------------------------------------------------------
__global__ void prep_weights(const float* __restrict__ w1, const float* __restrict__ w2,
                             const float* __restrict__ lng, const float* __restrict__ lnb,
                             const float* __restrict__ b1,
                             i64* __restrict__ W1L, i64* __restrict__ W2L,
                             float* __restrict__ B1s) {
    int i = blockIdx.x * 256 + threadIdx.x;
    if (i < 4608) {                               // W1L: 24 j16 * 3 kk * 64 lanes
        int n16 = i / 192, r = i - n16 * 192;
        int kk = r >> 6, lane = r & 63;
        int n = n16 * 16 + (lane & 15);
        int cb = kk * 32 + (lane >> 4) * 8;
        float s0 = lng[cb + 0] * w1[(cb + 0) * 384 + n];
        float s1 = lng[cb + 1] * w1[(cb + 1) * 384 + n];
        float s2 = lng[cb + 2] * w1[(cb + 2) * 384 + n];
        float s3 = lng[cb + 3] * w1[(cb + 3) * 384 + n];
        float s4 = lng[cb + 4] * w1[(cb + 4) * 384 + n];
        float s5 = lng[cb + 5] * w1[(cb + 5) * 384 + n];
        float s6 = lng[cb + 6] * w1[(cb + 6) * 384 + n];
        float s7 = lng[cb + 7] * w1[(cb + 7) * 384 + n];
        W1L[i] = mk64(pk4(s0, s1, s2, s3), pk4(s4, s5, s6, s7));
    } else if (i < 9216) {                        // W2L: 6 ct * 12 jk * 64 lanes
        int e = i - 4608;
        int r = e & 767, lane = r & 63, jk = r >> 6;
        int c = ((e / 768) * 16) + (lane & 15);
        int nb = jk * 32 + (lane >> 4) * 8;
        float s0 = w2[(nb + 0) * 96 + c], s1 = w2[(nb + 1) * 96 + c];
        float s2 = w2[(nb + 2) * 96 + c], s3 = w2[(nb + 3) * 96 + c];
        float s4 = w2[(nb + 4) * 96 + c], s5 = w2[(nb + 5) * 96 + c];
        float s6 = w2[(nb + 6) * 96 + c], s7 = w2[(nb + 7) * 96 + c];
        W2L[e] = mk64(pk4(s0, s1, s2, s3), pk4(s4, s5, s6, s7));
    } else if (i < 9600) {                        // B1s
        int n = i - 9216;
        float s = b1[n];
        for (int c = 0; c < 96; ++c) s += lnb[c] * w1[c * 384 + n];
        B1s[n] = s;
    }
}

// ---------------------------------------------------------------------------
// K0b: Toeplitz B-fragment table for the MFMA conv.
// BT[((c*49 + kd*7+kh)*64 + lane)*8] : 8 fp8, element j: k=(lane>>4)*8+j,
// n=lane&15, value = wgt[c][kd][kh][k-n] if 0<=k-n<7 else 0.
// ---------------------------------------------------------------------------
__global__ void prep_bt(const float* __restrict__ dww, unsigned char* __restrict__ BT) {
    int i = blockIdx.x * 256 + threadIdx.x;
    if (i >= 301056) return;                      // 96 * 49 * 64
    int lane = i & 63;
    int tap = (i >> 6) % 49;
    int c = i / 3136;
    int n = lane & 15, kg = lane >> 4;
    const float* wt = dww + c * 343 + tap * 7;    // tap = kd*7+kh -> kd*49+kh*7
    float e[8];
#pragma unroll
    for (int j = 0; j < 8; ++j) {
        int t = kg * 8 + j - n;
        e[j] = (t >= 0 && t < 7) ? wt[t] : 0.f;
    }
    u32 lo = pk4(e[0], e[1], e[2], e[3]);
    u32 hi = pk4(e[4], e[5], e[6], e[7]);
    *(u32*)&BT[(size_t)i * 8] = lo;
    *(u32*)&BT[(size_t)i * 8 + 4] = hi;
}

// ---------------------------------------------------------------------------
// K1: depthwise 7x7x7 conv via Toeplitz fp8 MFMA.
// Block 256 (4 waves) = (b, c, d-group of 4, h-quarter 16). Wave wv owns
// d = d0+wv, 16 h x 64 w (4 MFMA w-tiles). LDS: [10 pz][22 row][88 fp8],
// left-pad 3 (alignment) + zero-pad to 80 (NaN-safe), stride 88 (bank-clean).
// Per tap (kd,kh): 1 coalesced B-frag (global, L2) + per w-tile 1 ds_read_b64
// + 1 mfma_f32_16x16x32_fp8_fp8.
// PACKED==0: bf16 out to cw16[c][b*262144+pos]; ==1: hi bytes of d_out words.
// ---------------------------------------------------------------------------
template<int PACKED>
__global__ __launch_bounds__(256, 6) void dwconvM(const float* __restrict__ x,
                                                  const unsigned char* __restrict__ BT,
                                                  const float* __restrict__ dwb,
                                                  u16* __restrict__ cw16,
                                                  u16* __restrict__ o16) {
    __shared__ __align__(16) unsigned char tile[19360];   // 10*22*88
    const int tid = threadIdx.x;
    const int bx = blockIdx.x, c = blockIdx.y, b = blockIdx.z;
    const int d0 = (bx >> 2) * 4, h0 = (bx & 3) * 16;
    const float* xc = x + ((size_t)(b * 96 + c)) * 262144;

    // ---- stage fp8 tile: 10 pz x 22 rows x 20 u32 (80 fp8 + 8 pad ignored)
    for (int i = tid; i < 4400; i += 256) {
        int pz = i / 440;
        int rem = i - pz * 440;
        int row = rem / 20;
        int u = rem - row * 20;
        int d = d0 + pz - 3, h = h0 + row - 3;
        u32 pk = 0;
        if (((unsigned)d < 64u) && ((unsigned)h < 64u) && (u < 17)) {
            const float* xr = xc + d * 4096 + h * 64;
            int w0e = 4 * u - 3;                   // slot s=4u <-> w = s-3
            float e0 = ((unsigned)(w0e + 0) < 64u) ? xr[w0e + 0] : 0.f;
            float e1 = ((unsigned)(w0e + 1) < 64u) ? xr[w0e + 1] : 0.f;
            float e2 = ((unsigned)(w0e + 2) < 64u) ? xr[w0e + 2] : 0.f;
            float e3 = ((unsigned)(w0e + 3) < 64u) ? xr[w0e + 3] : 0.f;
            pk = pk4(e0, e1, e2, e3);
        }
        *(u32*)&tile[(pz * 22 + row) * 88 + u * 4] = pk;
    }
    __syncthreads();

    const int lane = tid & 63, wv = tid >> 6;
    const int n = lane & 15, g = lane >> 4;
    const unsigned char* BTc = BT + (size_t)c * 49 * 512;
    const int abase = n * 88 + 8 * g;              // A-frag: lane&15 = m(h), k-grp g

    f32x4 acc[4];
#pragma unroll
    for (int i = 0; i < 4; ++i) acc[i] = f32x4{0.f, 0.f, 0.f, 0.f};

#pragma unroll
    for (int kd = 0; kd < 7; ++kd) {
        const unsigned char* tb = &tile[(wv + kd) * 1936 + abase];
#pragma unroll
        for (int kh = 0; kh < 7; ++kh) {
            i64 bf = *(const i64*)(BTc + (size_t)(kd * 7 + kh) * 512 + lane * 8);
            const unsigned char* ab = tb + kh * 88;
#pragma unroll
            for (int wt = 0; wt < 4; ++wt) {
                i64 af = *(const i64*)(ab + 16 * wt);
                acc[wt] = __builtin_amdgcn_mfma_f32_16x16x32_fp8_fp8(af, bf, acc[wt], 0, 0, 0);
            }
        }
    }

    // ---- epilogue: D row m = 4g+q (h), col n (w = wt*16+n)
    const float bias = dwb[c];
    const int d = d0 + wv;
#pragma unroll
    for (int wt = 0; wt < 4; ++wt) {
#pragma unroll
        for (int q = 0; q < 4; ++q) {
            int h = h0 + 4 * g + q;
            int w = wt * 16 + n;
            u16 val = f2bf_rne(acc[wt][q] + bias);
            size_t pos = (size_t)b * 262144 + (size_t)d * 4096 + h * 64 + w;
            if (PACKED == 0)
                cw16[(size_t)c * 524288 + pos] = val;
            else
                o16[2 * ((size_t)(b * 96 + c) * 262144 + (size_t)d * 4096 + h * 64 + w) + 1] = val;
        }
    }
}

// ---------------------------------------------------------------------------
// K1-fallback: fp32-FMA conv (R5), used only when ws can't hold BT.
// ---------------------------------------------------------------------------
template<int PACKED>
__global__ __launch_bounds__(256, 5) void dwconvA(const float* __restrict__ x,
                                                  const float* __restrict__ dww,
                                                  const float* __restrict__ dwb,
                                                  u32* cw, u16* o16) {
    __shared__ u32 tile32[7920];                  // 10 * 792
    const int tid = threadIdx.x;
    const int bx = blockIdx.x, c = blockIdx.y, b = blockIdx.z;
    const int d0 = (bx >> 2) * 4, h0 = (bx & 3) * 16;
    const float* xc = x + ((size_t)(b * 96 + c)) * 262144;

    for (int i = tid; i < 7700; i += 256) {
        int pz = i / 770;
        int rem = i - pz * 770;
        int r2 = rem / 70;
        int col = rem - r2 * 70;
        int d = d0 + pz - 3, h = h0 + 2 * r2 - 3, w = col - 3;
        float lo = 0.f, hi = 0.f;
        if (((unsigned)d < 64u) && ((unsigned)w < 64u)) {
            int base = d * 4096 + h * 64 + w;
            if ((unsigned)h < 64u) lo = xc[base];
            if ((unsigned)(h + 1) < 64u) hi = xc[base + 64];
        }
        int a = pz * 792 + r2 * 72 + col;
        int aw = ((((a >> 2) ^ ((a >> 5) & 1)) << 2)) | (a & 3);
        tile32[aw] = (u32)f2bf_rne(lo) | ((u32)f2bf_rne(hi) << 16);
    }
    __syncthreads();

    const int tx = tid & 7, ty = (tid >> 3) & 7, tz = tid >> 6;
    float a0[8], a1[8];
#pragma unroll
    for (int i = 0; i < 8; ++i) { a0[i] = 0.f; a1[i] = 0.f; }

    for (int kd = 0; kd < 7; ++kd) {
        const float* Wk = dww + c * 343 + kd * 49;
        const int pz = tz + kd;
#pragma unroll
        for (int pr = 0; pr < 4; ++pr) {
            const int g0 = pz * 198 + (ty + pr) * 18 + (tx << 1);
            u32 rb[16];
#pragma unroll
            for (int k = 0; k < 4; ++k) {
                int g = g0 + k;
                int ga = (g ^ ((g >> 3) & 1)) << 2;
                *(u32x4*)&rb[4 * k] = *(const u32x4*)(tile32 + ga);
            }
            float rlo[16], rhi[16];
#pragma unroll
            for (int t = 0; t < 16; ++t) {
                rlo[t] = __builtin_bit_cast(float, rb[t] << 16);
                rhi[t] = __builtin_bit_cast(float, rb[t]);
            }
#pragma unroll
            for (int kw = 0; kw < 7; ++kw) {
                float wA = Wk[2 * pr * 7 + kw];
#pragma unroll
                for (int i = 0; i < 8; ++i) {
                    a0[i] = fmaf(rlo[kw + i], wA, a0[i]);
                    a1[i] = fmaf(rhi[kw + i], wA, a1[i]);
                }
                if (pr < 3) {
                    float wB = Wk[(2 * pr + 1) * 7 + kw];
#pragma unroll
                    for (int i = 0; i < 8; ++i) a0[i] = fmaf(rhi[kw + i], wB, a0[i]);
                }
                if (pr > 0) {
                    float wC = Wk[(2 * pr - 1) * 7 + kw];
#pragma unroll
                    for (int i = 0; i < 8; ++i) a1[i] = fmaf(rlo[kw + i], wC, a1[i]);
                }
            }
        }
    }

    const float bias = dwb[c];
    const int d = d0 + tz;
    const int hA = h0 + 2 * ty;
    if (PACKED == 0) {
        const int p = b * 262144 + d * 4096 + hA * 64 + 8 * tx;
        u32* dst = cw + c * 262144 + (p >> 1);
#pragma unroll
        for (int k = 0; k < 4; ++k)
            dst[k] = (u32)f2bf_rne(a0[2 * k] + bias) | ((u32)f2bf_rne(a0[2 * k + 1] + bias) << 16);
        u32* dst1 = dst + 32;
#pragma unroll
        for (int k = 0; k < 4; ++k)
            dst1[k] = (u32)f2bf_rne(a1[2 * k] + bias) | ((u32)f2bf_rne(a1[2 * k + 1] + bias) << 16);
    } else {
        size_t e = ((size_t)(b * 96 + c)) * 262144 + d * 4096 + hA * 64 + 8 * tx;
#pragma unroll
        for (int i = 0; i < 8; ++i) o16[2 * (e + i) + 1] = f2bf_rne(a0[i] + bias);
#pragma unroll
        for (int i = 0; i < 8; ++i) o16[2 * (e + 64 + i) + 1] = f2bf_rne(a1[i] + bias);
    }
}

// ---------------------------------------------------------------------------
// K2: wave-independent LN+MLP (unchanged from R5, ~115 us).
// ---------------------------------------------------------------------------
template<int CWP, int WF>
__global__ __launch_bounds__(256, 4) void mlp3(const void* cwsrc,
                                               const i64* __restrict__ W1L,
                                               const i64* __restrict__ W2L,
                                               const float* __restrict__ B1s,
                                               const float* __restrict__ w1f,
                                               const float* __restrict__ w2f,
                                               const float* __restrict__ lng,
                                               const float* __restrict__ lnb,
                                               const float* __restrict__ b1g,
                                               const float* __restrict__ b2g,
                                               const float* __restrict__ gam,
                                               const float* __restrict__ x,
                                               float* __restrict__ out) {
    __shared__ __align__(16) unsigned char HS[4][2][1152];  // [wave][tile][16p * 72B]

    const int tid = threadIdx.x;
    const int wv = tid >> 6, lane = tid & 63;
    const int p = lane & 15, G = lane >> 4;
    const int pos0 = blockIdx.x * 128 + wv * 32;
    const int b = pos0 >> 18, prel0 = pos0 & 262143;
    unsigned char* hsw = &HS[wv][0][0];

    i64 aF[2][3];
#pragma unroll
    for (int t = 0; t < 2; ++t) {
        float v[3][8];
        if (CWP == 0) {
            const u16* cw16 = (const u16*)cwsrc;
#pragma unroll
            for (int kk = 0; kk < 3; ++kk)
#pragma unroll
                for (int m = 0; m < 8; ++m) {
                    int c = kk * 32 + G * 8 + m;
                    v[kk][m] = bf2f(cw16[(size_t)c * 524288 + pos0 + t * 16 + p]);
                }
        } else {
            const u32* ow = (const u32*)cwsrc;
#pragma unroll
            for (int kk = 0; kk < 3; ++kk)
#pragma unroll
                for (int m = 0; m < 8; ++m) {
                    int c = kk * 32 + G * 8 + m;
                    v[kk][m] = bf2f((u16)(ow[((size_t)(b * 96 + c)) * 262144 + prel0 + t * 16 + p] >> 16));
                }
        }
        float s = 0.f, sq = 0.f;
#pragma unroll
        for (int kk = 0; kk < 3; ++kk)
#pragma unroll
            for (int m = 0; m < 8; ++m) { s += v[kk][m]; sq += v[kk][m] * v[kk][m]; }
        s += __shfl_xor(s, 16); sq += __shfl_xor(sq, 16);
        s += __shfl_xor(s, 32); sq += __shfl_xor(sq, 32);
        float mu = s * (1.f / 96.f);
        float rstd = rsqrtf(sq * (1.f / 96.f) - mu * mu + 1e-5f);
#pragma unroll
        for (int kk = 0; kk < 3; ++kk) {
            float n0 = (v[kk][0] - mu) * rstd, n1 = (v[kk][1] - mu) * rstd;
            float n2 = (v[kk][2] - mu) * rstd, n3 = (v[kk][3] - mu) * rstd;
            float n4 = (v[kk][4] - mu) * rstd, n5 = (v[kk][5] - mu) * rstd;
            float n6 = (v[kk][6] - mu) * rstd, n7 = (v[kk][7] - mu) * rstd;
            aF[t][kk] = mk64(pk4(n0, n1, n2, n3), pk4(n4, n5, n6, n7));
        }
    }

    f32x4 acc[2][6];
#pragma unroll
    for (int t = 0; t < 2; ++t)
#pragma unroll
        for (int i = 0; i < 6; ++i) acc[t][i] = f32x4{0.f, 0.f, 0.f, 0.f};

    for (int j = 0; j < 6; ++j) {
        i64 wf[12];
#pragma unroll
        for (int q = 0; q < 12; ++q) {
            if (WF == 0) {
                wf[q] = W1L[(j * 12 + q) * 64 + lane];
            } else {
                int nt = q / 3, kk = q - nt * 3;
                int nn = (j * 4 + nt) * 16 + p;
                int cb = kk * 32 + G * 8;
                wf[q] = mk64(
                    pk4(lng[cb + 0] * w1f[(cb + 0) * 384 + nn], lng[cb + 1] * w1f[(cb + 1) * 384 + nn],
                        lng[cb + 2] * w1f[(cb + 2) * 384 + nn], lng[cb + 3] * w1f[(cb + 3) * 384 + nn]),
                    pk4(lng[cb + 4] * w1f[(cb + 4) * 384 + nn], lng[cb + 5] * w1f[(cb + 5) * 384 + nn],
                        lng[cb + 6] * w1f[(cb + 6) * 384 + nn], lng[cb + 7] * w1f[(cb + 7) * 384 + nn]));
            }
        }
        f32x4 bb[4];
#pragma unroll
        for (int nt = 0; nt < 4; ++nt)
            bb[nt] = *(const f32x4*)&B1s[(j * 4 + nt) * 16 + 4 * G];

#pragma unroll
        for (int t = 0; t < 2; ++t) {
            f32x4 c1[4];
#pragma unroll
            for (int nt = 0; nt < 4; ++nt) {
                c1[nt] = f32x4{0.f, 0.f, 0.f, 0.f};
#pragma unroll
                for (int kk = 0; kk < 3; ++kk)
                    c1[nt] = __builtin_amdgcn_mfma_f32_16x16x32_fp8_fp8(wf[nt * 3 + kk], aF[t][kk], c1[nt], 0, 0, 0);
            }
#pragma unroll
            for (int nt = 0; nt < 4; ++nt) {
                float g0 = gelu_fast(c1[nt][0] + bb[nt][0]);
                float g1 = gelu_fast(c1[nt][1] + bb[nt][1]);
                float g2 = gelu_fast(c1[nt][2] + bb[nt][2]);
                float g3 = gelu_fast(c1[nt][3] + bb[nt][3]);
                *(u32*)&hsw[t * 1152 + p * 72 + nt * 16 + 4 * G] = pk4(g0, g1, g2, g3);
            }
        }

        i64 w2r[12];
#pragma unroll
        for (int q = 0; q < 12; ++q) {
            int ct = q >> 1, kkj = q & 1;
            if (WF == 0) {
                w2r[q] = W2L[(ct * 12 + j * 2 + kkj) * 64 + lane];
            } else {
                int cc = ct * 16 + p;
                int nb = (j * 2 + kkj) * 32 + G * 8;
                w2r[q] = mk64(
                    pk4(w2f[(nb + 0) * 96 + cc], w2f[(nb + 1) * 96 + cc],
                        w2f[(nb + 2) * 96 + cc], w2f[(nb + 3) * 96 + cc]),
                    pk4(w2f[(nb + 4) * 96 + cc], w2f[(nb + 5) * 96 + cc],
                        w2f[(nb + 6) * 96 + cc], w2f[(nb + 7) * 96 + cc]));
            }
        }

        asm volatile("s_waitcnt lgkmcnt(0)" ::: "memory");
        __builtin_amdgcn_sched_barrier(0);

        i64 hF[2][2];
#pragma unroll
        for (int t = 0; t < 2; ++t)
#pragma unroll
            for (int kkj = 0; kkj < 2; ++kkj)
                hF[t][kkj] = *(const i64*)&hsw[t * 1152 + p * 72 + kkj * 32 + G * 8];

#pragma unroll
        for (int ct = 0; ct < 6; ++ct)
#pragma unroll
            for (int kkj = 0; kkj < 2; ++kkj) {
#pragma unroll
                for (int t = 0; t < 2; ++t)
                    acc[t][ct] = __builtin_amdgcn_mfma_f32_16x16x32_fp8_fp8(hF[t][kkj], w2r[ct * 2 + kkj], acc[t][ct], 0, 0, 0);
            }
    }

#pragma unroll
    for (int ct = 0; ct < 6; ++ct) {
        int c = ct * 16 + p;
        float b2c = b2g[c], gc = gam[c];
#pragma unroll
        for (int t = 0; t < 2; ++t) {
            size_t xi = ((size_t)(b * 96 + c)) * 262144 + prel0 + t * 16 + G * 4;
            f32x4 xv = *(const f32x4*)&x[xi];
            f32x4 o;
#pragma unroll
            for (int r = 0; r < 4; ++r) o[r] = (acc[t][ct][r] + b2c) * gc + xv[r];
            *(f32x4*)&out[xi] = o;
        }
    }
}

// ---------------------------------------------------------------------------
extern "C" void kernel_launch(void* const* d_in, const int* in_sizes, int n_in,
                              void* d_out, int out_size, void* d_ws, size_t ws_size,
                              hipStream_t stream) {
    const float* x   = (const float*)d_in[0];
    const float* dww = (const float*)d_in[1];
    const float* dwb = (const float*)d_in[2];
    const float* lng = (const float*)d_in[3];
    const float* lnb = (const float*)d_in[4];
    const float* w1  = (const float*)d_in[5];
    const float* b1  = (const float*)d_in[6];
    const float* w2  = (const float*)d_in[7];
    const float* b2  = (const float*)d_in[8];
    const float* gam = (const float*)d_in[9];
    float* out = (float*)d_out;

    // ws: W1L @0 (36864) | W2L (36864) | B1s (1536) | BT @75264 (2408448)
    //     | cw @2483712 (100663296)
    const size_t NEED_W  = 75264;
    const size_t NEED_BT = 75264 + 2408448ull;              // 2,483,712
    const size_t NEED_FULL = NEED_BT + 100663296ull;        // 103,147,008
    const bool wsW  = ws_size >= NEED_W;
    const bool wsBT = ws_size >= NEED_BT;
    const bool wsCW = ws_size >= NEED_FULL;

    i64* W1L = (i64*)d_ws;
    i64* W2L = (i64*)((char*)d_ws + 36864);
    float* B1s = (float*)((char*)d_ws + 73728);
    unsigned char* BT = (unsigned char*)d_ws + 75264;
    u32* cw = (u32*)((char*)d_ws + 2483712);

    if (wsW)
        hipLaunchKernelGGL(prep_weights, dim3(38), dim3(256), 0, stream,
                           w1, w2, lng, lnb, b1, W1L, W2L, B1s);
    if (wsBT)
        hipLaunchKernelGGL(prep_bt, dim3(1176), dim3(256), 0, stream, dww, BT);

    dim3 g1(64, 96, 2), blk(256);
    if (wsCW)
        hipLaunchKernelGGL((dwconvM<0>), g1, blk, 0, stream, x, BT, dwb, (u16*)cw, (u16*)d_out);
    else if (wsBT)
        hipLaunchKernelGGL((dwconvM<1>), g1, blk, 0, stream, x, BT, dwb, (u16*)cw, (u16*)d_out);
    else
        hipLaunchKernelGGL((dwconvA<1>), g1, blk, 0, stream, x, dww, dwb, cw, (u16*)d_out);

    dim3 g2(4096), blk2(256);
    if (wsCW)
        hipLaunchKernelGGL((mlp3<0, 0>), g2, blk2, 0, stream, (const void*)cw,
                           W1L, W2L, B1s, w1, w2, lng, lnb, b1, b2, gam, x, out);
    else if (wsW)
        hipLaunchKernelGGL((mlp3<1, 0>), g2, blk2, 0, stream, (const void*)d_out,
                           W1L, W2L, B1s, w1, w2, lng, lnb, b1, b2, gam, x, out);
    else
        hipLaunchKernelGGL((mlp3<1, 1>), g2, blk2, 0, stream, (const void*)d_out,
                           W1L, W2L, B1s, w1, w2, lng, lnb, b1, b2, gam, x, out);
}

// Round 7
// 449.809 us; speedup vs baseline: 1.8164x; 1.0557x over previous
//
#include <hip/hip_runtime.h>

typedef unsigned int u32;
typedef unsigned short u16;
typedef unsigned long long u64;
typedef long i64;
typedef float f32x4 __attribute__((ext_vector_type(4)));
typedef u32 u32x4 __attribute__((ext_vector_type(4)));

__device__ __forceinline__ u16 f2bf_rne(float f) {
    return __builtin_bit_cast(u16, (__bf16)f);
}
__device__ __forceinline__ float bf2f(u16 h) {
    return __builtin_bit_cast(float, ((u32)h) << 16);
}
__device__ __forceinline__ float gelu_fast(float v) {
    float t = __builtin_amdgcn_exp2f(v * -2.4554673f);
    return v * __builtin_amdgcn_rcpf(1.f + t);
}
__device__ __forceinline__ i64 mk64(u32 lo, u32 hi) {
    return (i64)(((u64)hi << 32) | (u64)lo);
}
__device__ __forceinline__ u32 pk4(float a, float b, float c, float d) {
    u32 w = (u32)__builtin_amdgcn_cvt_pk_fp8_f32(a, b, 0, false);
    return (u32)__builtin_amdgcn_cvt_pk_fp8_f32(c, d, (int)w, true);
}

// ---------------------------------------------------------------------------
// K0: prep — MLP weights in MFMA-fragment order (unchanged from R5).
// ---------------------------------------------------------------------------
__global__ void prep_weights(const float* __restrict__ w1, const float* __restrict__ w2,
                             const float* __restrict__ lng, const float* __restrict__ lnb,
                             const float* __restrict__ b1,
                             i64* __restrict__ W1L, i64* __restrict__ W2L,
                             float* __restrict__ B1s) {
    int i = blockIdx.x * 256 + threadIdx.x;
    if (i < 4608) {                               // W1L: 24 j16 * 3 kk * 64 lanes
        int n16 = i / 192, r = i - n16 * 192;
        int kk = r >> 6, lane = r & 63;
        int n = n16 * 16 + (lane & 15);
        int cb = kk * 32 + (lane >> 4) * 8;
        float s0 = lng[cb + 0] * w1[(cb + 0) * 384 + n];
        float s1 = lng[cb + 1] * w1[(cb + 1) * 384 + n];
        float s2 = lng[cb + 2] * w1[(cb + 2) * 384 + n];
        float s3 = lng[cb + 3] * w1[(cb + 3) * 384 + n];
        float s4 = lng[cb + 4] * w1[(cb + 4) * 384 + n];
        float s5 = lng[cb + 5] * w1[(cb + 5) * 384 + n];
        float s6 = lng[cb + 6] * w1[(cb + 6) * 384 + n];
        float s7 = lng[cb + 7] * w1[(cb + 7) * 384 + n];
        W1L[i] = mk64(pk4(s0, s1, s2, s3), pk4(s4, s5, s6, s7));
    } else if (i < 9216) {                        // W2L: 6 ct * 12 jk * 64 lanes
        int e = i - 4608;
        int r = e & 767, lane = r & 63, jk = r >> 6;
        int c = ((e / 768) * 16) + (lane & 15);
        int nb = jk * 32 + (lane >> 4) * 8;
        float s0 = w2[(nb + 0) * 96 + c], s1 = w2[(nb + 1) * 96 + c];
        float s2 = w2[(nb + 2) * 96 + c], s3 = w2[(nb + 3) * 96 + c];
        float s4 = w2[(nb + 4) * 96 + c], s5 = w2[(nb + 5) * 96 + c];
        float s6 = w2[(nb + 6) * 96 + c], s7 = w2[(nb + 7) * 96 + c];
        W2L[e] = mk64(pk4(s0, s1, s2, s3), pk4(s4, s5, s6, s7));
    } else if (i < 9600) {                        // B1s
        int n = i - 9216;
        float s = b1[n];
        for (int c = 0; c < 96; ++c) s += lnb[c] * w1[c * 384 + n];
        B1s[n] = s;
    }
}

// ---------------------------------------------------------------------------
// K0b: Toeplitz B-fragment table (unchanged from R6).
// ---------------------------------------------------------------------------
__global__ void prep_bt(const float* __restrict__ dww, unsigned char* __restrict__ BT) {
    int i = blockIdx.x * 256 + threadIdx.x;
    if (i >= 301056) return;                      // 96 * 49 * 64
    int lane = i & 63;
    int tap = (i >> 6) % 49;
    int c = i / 3136;
    int n = lane & 15, kg = lane >> 4;
    const float* wt = dww + c * 343 + tap * 7;
    float e[8];
#pragma unroll
    for (int j = 0; j < 8; ++j) {
        int t = kg * 8 + j - n;
        e[j] = (t >= 0 && t < 7) ? wt[t] : 0.f;
    }
    u32 lo = pk4(e[0], e[1], e[2], e[3]);
    u32 hi = pk4(e[4], e[5], e[6], e[7]);
    *(u32*)&BT[(size_t)i * 8] = lo;
    *(u32*)&BT[(size_t)i * 8 + 4] = hi;
}

// ---------------------------------------------------------------------------
// K1: Toeplitz fp8 MFMA conv, v2.
//  - B-frags register double-buffered across kd (bfC/bfN, static indexing):
//    kd+1's 7 global loads issue before kd's 28 ds_read + 28 MFMA -> latency hidden.
//  - staging vectorized: interior u in [1,15] one unaligned 16B load, edges scalar.
// ---------------------------------------------------------------------------
template<int PACKED>
__global__ __launch_bounds__(256, 6) void dwconvM(const float* __restrict__ x,
                                                  const unsigned char* __restrict__ BT,
                                                  const float* __restrict__ dwb,
                                                  u16* __restrict__ cw16,
                                                  u16* __restrict__ o16) {
    __shared__ __align__(16) unsigned char tile[19360];   // 10*22*88
    const int tid = threadIdx.x;
    const int bx = blockIdx.x, c = blockIdx.y, b = blockIdx.z;
    const int d0 = (bx >> 2) * 4, h0 = (bx & 3) * 16;
    const float* xc = x + ((size_t)(b * 96 + c)) * 262144;

    // ---- stage fp8 tile: 10 pz x 22 rows x 20 u32 (slot s = w+3)
    for (int i = tid; i < 4400; i += 256) {
        int pz = i / 440;
        int rem = i - pz * 440;
        int row = rem / 20;
        int u = rem - row * 20;
        int d = d0 + pz - 3, h = h0 + row - 3;
        u32 pk = 0;
        if (((unsigned)d < 64u) && ((unsigned)h < 64u)) {
            const float* xr = xc + d * 4096 + h * 64;
            if (u >= 1 && u <= 15) {               // w = 4u-3 .. 4u, all in-range
                float e[4];
                __builtin_memcpy(e, xr + 4 * u - 3, 16);
                pk = pk4(e[0], e[1], e[2], e[3]);
            } else if (u == 0) {                   // only w=0 (slot 3) valid
                pk = pk4(0.f, 0.f, 0.f, xr[0]);
            } else if (u == 16) {                  // w=61,62,63 valid
                pk = pk4(xr[61], xr[62], xr[63], 0.f);
            }                                       // u 17..19 stay zero
        }
        *(u32*)&tile[(pz * 22 + row) * 88 + u * 4] = pk;
    }
    __syncthreads();

    const int lane = tid & 63, wv = tid >> 6;
    const int n = lane & 15, g = lane >> 4;
    const unsigned char* BTl = BT + (size_t)c * 49 * 512 + (size_t)lane * 8;
    const int abase = n * 88 + 8 * g;

    f32x4 acc[4];
#pragma unroll
    for (int i = 0; i < 4; ++i) acc[i] = f32x4{0.f, 0.f, 0.f, 0.f};

    i64 bfC[7], bfN[7];
#pragma unroll
    for (int kh = 0; kh < 7; ++kh)
        bfC[kh] = *(const i64*)(BTl + (size_t)kh * 512);

#pragma unroll
    for (int kd = 0; kd < 7; ++kd) {
        // prefetch next kd's B-frags (7 x 8B, L2) before this kd's MFMA chain
#pragma unroll
        for (int kh = 0; kh < 7; ++kh)
            bfN[kh] = (kd < 6) ? *(const i64*)(BTl + (size_t)((kd + 1) * 7 + kh) * 512)
                               : (i64)0;
        const unsigned char* tb = &tile[(wv + kd) * 1936 + abase];
#pragma unroll
        for (int kh = 0; kh < 7; ++kh) {
            const unsigned char* ab = tb + kh * 88;
#pragma unroll
            for (int wt = 0; wt < 4; ++wt) {
                i64 af = *(const i64*)(ab + 16 * wt);
                acc[wt] = __builtin_amdgcn_mfma_f32_16x16x32_fp8_fp8(af, bfC[kh], acc[wt], 0, 0, 0);
            }
        }
#pragma unroll
        for (int kh = 0; kh < 7; ++kh) bfC[kh] = bfN[kh];
    }

    // ---- epilogue: D row m = 4g+q (h), col n (w = wt*16+n)
    const float bias = dwb[c];
    const int d = d0 + wv;
#pragma unroll
    for (int wt = 0; wt < 4; ++wt) {
#pragma unroll
        for (int q = 0; q < 4; ++q) {
            int h = h0 + 4 * g + q;
            int w = wt * 16 + n;
            u16 val = f2bf_rne(acc[wt][q] + bias);
            size_t pos = (size_t)b * 262144 + (size_t)d * 4096 + h * 64 + w;
            if (PACKED == 0)
                cw16[(size_t)c * 524288 + pos] = val;
            else
                o16[2 * ((size_t)(b * 96 + c) * 262144 + (size_t)d * 4096 + h * 64 + w) + 1] = val;
        }
    }
}

// ---------------------------------------------------------------------------
// K1-fallback: fp32-FMA conv (R5), used only when ws can't hold BT.
// ---------------------------------------------------------------------------
template<int PACKED>
__global__ __launch_bounds__(256, 5) void dwconvA(const float* __restrict__ x,
                                                  const float* __restrict__ dww,
                                                  const float* __restrict__ dwb,
                                                  u32* cw, u16* o16) {
    __shared__ u32 tile32[7920];                  // 10 * 792
    const int tid = threadIdx.x;
    const int bx = blockIdx.x, c = blockIdx.y, b = blockIdx.z;
    const int d0 = (bx >> 2) * 4, h0 = (bx & 3) * 16;
    const float* xc = x + ((size_t)(b * 96 + c)) * 262144;

    for (int i = tid; i < 7700; i += 256) {
        int pz = i / 770;
        int rem = i - pz * 770;
        int r2 = rem / 70;
        int col = rem - r2 * 70;
        int d = d0 + pz - 3, h = h0 + 2 * r2 - 3, w = col - 3;
        float lo = 0.f, hi = 0.f;
        if (((unsigned)d < 64u) && ((unsigned)w < 64u)) {
            int base = d * 4096 + h * 64 + w;
            if ((unsigned)h < 64u) lo = xc[base];
            if ((unsigned)(h + 1) < 64u) hi = xc[base + 64];
        }
        int a = pz * 792 + r2 * 72 + col;
        int aw = ((((a >> 2) ^ ((a >> 5) & 1)) << 2)) | (a & 3);
        tile32[aw] = (u32)f2bf_rne(lo) | ((u32)f2bf_rne(hi) << 16);
    }
    __syncthreads();

    const int tx = tid & 7, ty = (tid >> 3) & 7, tz = tid >> 6;
    float a0[8], a1[8];
#pragma unroll
    for (int i = 0; i < 8; ++i) { a0[i] = 0.f; a1[i] = 0.f; }

    for (int kd = 0; kd < 7; ++kd) {
        const float* Wk = dww + c * 343 + kd * 49;
        const int pz = tz + kd;
#pragma unroll
        for (int pr = 0; pr < 4; ++pr) {
            const int g0 = pz * 198 + (ty + pr) * 18 + (tx << 1);
            u32 rb[16];
#pragma unroll
            for (int k = 0; k < 4; ++k) {
                int g = g0 + k;
                int ga = (g ^ ((g >> 3) & 1)) << 2;
                *(u32x4*)&rb[4 * k] = *(const u32x4*)(tile32 + ga);
            }
            float rlo[16], rhi[16];
#pragma unroll
            for (int t = 0; t < 16; ++t) {
                rlo[t] = __builtin_bit_cast(float, rb[t] << 16);
                rhi[t] = __builtin_bit_cast(float, rb[t]);
            }
#pragma unroll
            for (int kw = 0; kw < 7; ++kw) {
                float wA = Wk[2 * pr * 7 + kw];
#pragma unroll
                for (int i = 0; i < 8; ++i) {
                    a0[i] = fmaf(rlo[kw + i], wA, a0[i]);
                    a1[i] = fmaf(rhi[kw + i], wA, a1[i]);
                }
                if (pr < 3) {
                    float wB = Wk[(2 * pr + 1) * 7 + kw];
#pragma unroll
                    for (int i = 0; i < 8; ++i) a0[i] = fmaf(rhi[kw + i], wB, a0[i]);
                }
                if (pr > 0) {
                    float wC = Wk[(2 * pr - 1) * 7 + kw];
#pragma unroll
                    for (int i = 0; i < 8; ++i) a1[i] = fmaf(rlo[kw + i], wC, a1[i]);
                }
            }
        }
    }

    const float bias = dwb[c];
    const int d = d0 + tz;
    const int hA = h0 + 2 * ty;
    if (PACKED == 0) {
        const int p = b * 262144 + d * 4096 + hA * 64 + 8 * tx;
        u32* dst = cw + c * 262144 + (p >> 1);
#pragma unroll
        for (int k = 0; k < 4; ++k)
            dst[k] = (u32)f2bf_rne(a0[2 * k] + bias) | ((u32)f2bf_rne(a0[2 * k + 1] + bias) << 16);
        u32* dst1 = dst + 32;
#pragma unroll
        for (int k = 0; k < 4; ++k)
            dst1[k] = (u32)f2bf_rne(a1[2 * k] + bias) | ((u32)f2bf_rne(a1[2 * k + 1] + bias) << 16);
    } else {
        size_t e = ((size_t)(b * 96 + c)) * 262144 + d * 4096 + hA * 64 + 8 * tx;
#pragma unroll
        for (int i = 0; i < 8; ++i) o16[2 * (e + i) + 1] = f2bf_rne(a0[i] + bias);
#pragma unroll
        for (int i = 0; i < 8; ++i) o16[2 * (e + 64 + i) + 1] = f2bf_rne(a1[i] + bias);
    }
}

// ---------------------------------------------------------------------------
// K2: wave-independent LN+MLP (unchanged from R5, ~115 us).
// ---------------------------------------------------------------------------
template<int CWP, int WF>
__global__ __launch_bounds__(256, 4) void mlp3(const void* cwsrc,
                                               const i64* __restrict__ W1L,
                                               const i64* __restrict__ W2L,
                                               const float* __restrict__ B1s,
                                               const float* __restrict__ w1f,
                                               const float* __restrict__ w2f,
                                               const float* __restrict__ lng,
                                               const float* __restrict__ lnb,
                                               const float* __restrict__ b1g,
                                               const float* __restrict__ b2g,
                                               const float* __restrict__ gam,
                                               const float* __restrict__ x,
                                               float* __restrict__ out) {
    __shared__ __align__(16) unsigned char HS[4][2][1152];  // [wave][tile][16p * 72B]

    const int tid = threadIdx.x;
    const int wv = tid >> 6, lane = tid & 63;
    const int p = lane & 15, G = lane >> 4;
    const int pos0 = blockIdx.x * 128 + wv * 32;
    const int b = pos0 >> 18, prel0 = pos0 & 262143;
    unsigned char* hsw = &HS[wv][0][0];

    i64 aF[2][3];
#pragma unroll
    for (int t = 0; t < 2; ++t) {
        float v[3][8];
        if (CWP == 0) {
            const u16* cw16 = (const u16*)cwsrc;
#pragma unroll
            for (int kk = 0; kk < 3; ++kk)
#pragma unroll
                for (int m = 0; m < 8; ++m) {
                    int c = kk * 32 + G * 8 + m;
                    v[kk][m] = bf2f(cw16[(size_t)c * 524288 + pos0 + t * 16 + p]);
                }
        } else {
            const u32* ow = (const u32*)cwsrc;
#pragma unroll
            for (int kk = 0; kk < 3; ++kk)
#pragma unroll
                for (int m = 0; m < 8; ++m) {
                    int c = kk * 32 + G * 8 + m;
                    v[kk][m] = bf2f((u16)(ow[((size_t)(b * 96 + c)) * 262144 + prel0 + t * 16 + p] >> 16));
                }
        }
        float s = 0.f, sq = 0.f;
#pragma unroll
        for (int kk = 0; kk < 3; ++kk)
#pragma unroll
            for (int m = 0; m < 8; ++m) { s += v[kk][m]; sq += v[kk][m] * v[kk][m]; }
        s += __shfl_xor(s, 16); sq += __shfl_xor(sq, 16);
        s += __shfl_xor(s, 32); sq += __shfl_xor(sq, 32);
        float mu = s * (1.f / 96.f);
        float rstd = rsqrtf(sq * (1.f / 96.f) - mu * mu + 1e-5f);
#pragma unroll
        for (int kk = 0; kk < 3; ++kk) {
            float n0 = (v[kk][0] - mu) * rstd, n1 = (v[kk][1] - mu) * rstd;
            float n2 = (v[kk][2] - mu) * rstd, n3 = (v[kk][3] - mu) * rstd;
            float n4 = (v[kk][4] - mu) * rstd, n5 = (v[kk][5] - mu) * rstd;
            float n6 = (v[kk][6] - mu) * rstd, n7 = (v[kk][7] - mu) * rstd;
            aF[t][kk] = mk64(pk4(n0, n1, n2, n3), pk4(n4, n5, n6, n7));
        }
    }

    f32x4 acc[2][6];
#pragma unroll
    for (int t = 0; t < 2; ++t)
#pragma unroll
        for (int i = 0; i < 6; ++i) acc[t][i] = f32x4{0.f, 0.f, 0.f, 0.f};

    for (int j = 0; j < 6; ++j) {
        i64 wf[12];
#pragma unroll
        for (int q = 0; q < 12; ++q) {
            if (WF == 0) {
                wf[q] = W1L[(j * 12 + q) * 64 + lane];
            } else {
                int nt = q / 3, kk = q - nt * 3;
                int nn = (j * 4 + nt) * 16 + p;
                int cb = kk * 32 + G * 8;
                wf[q] = mk64(
                    pk4(lng[cb + 0] * w1f[(cb + 0) * 384 + nn], lng[cb + 1] * w1f[(cb + 1) * 384 + nn],
                        lng[cb + 2] * w1f[(cb + 2) * 384 + nn], lng[cb + 3] * w1f[(cb + 3) * 384 + nn]),
                    pk4(lng[cb + 4] * w1f[(cb + 4) * 384 + nn], lng[cb + 5] * w1f[(cb + 5) * 384 + nn],
                        lng[cb + 6] * w1f[(cb + 6) * 384 + nn], lng[cb + 7] * w1f[(cb + 7) * 384 + nn]));
            }
        }
        f32x4 bb[4];
#pragma unroll
        for (int nt = 0; nt < 4; ++nt)
            bb[nt] = *(const f32x4*)&B1s[(j * 4 + nt) * 16 + 4 * G];

#pragma unroll
        for (int t = 0; t < 2; ++t) {
            f32x4 c1[4];
#pragma unroll
            for (int nt = 0; nt < 4; ++nt) {
                c1[nt] = f32x4{0.f, 0.f, 0.f, 0.f};
#pragma unroll
                for (int kk = 0; kk < 3; ++kk)
                    c1[nt] = __builtin_amdgcn_mfma_f32_16x16x32_fp8_fp8(wf[nt * 3 + kk], aF[t][kk], c1[nt], 0, 0, 0);
            }
#pragma unroll
            for (int nt = 0; nt < 4; ++nt) {
                float g0 = gelu_fast(c1[nt][0] + bb[nt][0]);
                float g1 = gelu_fast(c1[nt][1] + bb[nt][1]);
                float g2 = gelu_fast(c1[nt][2] + bb[nt][2]);
                float g3 = gelu_fast(c1[nt][3] + bb[nt][3]);
                *(u32*)&hsw[t * 1152 + p * 72 + nt * 16 + 4 * G] = pk4(g0, g1, g2, g3);
            }
        }

        i64 w2r[12];
#pragma unroll
        for (int q = 0; q < 12; ++q) {
            int ct = q >> 1, kkj = q & 1;
            if (WF == 0) {
                w2r[q] = W2L[(ct * 12 + j * 2 + kkj) * 64 + lane];
            } else {
                int cc = ct * 16 + p;
                int nb = (j * 2 + kkj) * 32 + G * 8;
                w2r[q] = mk64(
                    pk4(w2f[(nb + 0) * 96 + cc], w2f[(nb + 1) * 96 + cc],
                        w2f[(nb + 2) * 96 + cc], w2f[(nb + 3) * 96 + cc]),
                    pk4(w2f[(nb + 4) * 96 + cc], w2f[(nb + 5) * 96 + cc],
                        w2f[(nb + 6) * 96 + cc], w2f[(nb + 7) * 96 + cc]));
            }
        }

        asm volatile("s_waitcnt lgkmcnt(0)" ::: "memory");
        __builtin_amdgcn_sched_barrier(0);

        i64 hF[2][2];
#pragma unroll
        for (int t = 0; t < 2; ++t)
#pragma unroll
            for (int kkj = 0; kkj < 2; ++kkj)
                hF[t][kkj] = *(const i64*)&hsw[t * 1152 + p * 72 + kkj * 32 + G * 8];

#pragma unroll
        for (int ct = 0; ct < 6; ++ct)
#pragma unroll
            for (int kkj = 0; kkj < 2; ++kkj) {
#pragma unroll
                for (int t = 0; t < 2; ++t)
                    acc[t][ct] = __builtin_amdgcn_mfma_f32_16x16x32_fp8_fp8(hF[t][kkj], w2r[ct * 2 + kkj], acc[t][ct], 0, 0, 0);
            }
    }

#pragma unroll
    for (int ct = 0; ct < 6; ++ct) {
        int c = ct * 16 + p;
        float b2c = b2g[c], gc = gam[c];
#pragma unroll
        for (int t = 0; t < 2; ++t) {
            size_t xi = ((size_t)(b * 96 + c)) * 262144 + prel0 + t * 16 + G * 4;
            f32x4 xv = *(const f32x4*)&x[xi];
            f32x4 o;
#pragma unroll
            for (int r = 0; r < 4; ++r) o[r] = (acc[t][ct][r] + b2c) * gc + xv[r];
            *(f32x4*)&out[xi] = o;
        }
    }
}

// ---------------------------------------------------------------------------
extern "C" void kernel_launch(void* const* d_in, const int* in_sizes, int n_in,
                              void* d_out, int out_size, void* d_ws, size_t ws_size,
                              hipStream_t stream) {
    const float* x   = (const float*)d_in[0];
    const float* dww = (const float*)d_in[1];
    const float* dwb = (const float*)d_in[2];
    const float* lng = (const float*)d_in[3];
    const float* lnb = (const float*)d_in[4];
    const float* w1  = (const float*)d_in[5];
    const float* b1  = (const float*)d_in[6];
    const float* w2  = (const float*)d_in[7];
    const float* b2  = (const float*)d_in[8];
    const float* gam = (const float*)d_in[9];
    float* out = (float*)d_out;

    // ws: W1L @0 (36864) | W2L (36864) | B1s (1536) | BT @75264 (2408448)
    //     | cw @2483712 (100663296)
    const size_t NEED_W  = 75264;
    const size_t NEED_BT = 75264 + 2408448ull;              // 2,483,712
    const size_t NEED_FULL = NEED_BT + 100663296ull;        // 103,147,008
    const bool wsW  = ws_size >= NEED_W;
    const bool wsBT = ws_size >= NEED_BT;
    const bool wsCW = ws_size >= NEED_FULL;

    i64* W1L = (i64*)d_ws;
    i64* W2L = (i64*)((char*)d_ws + 36864);
    float* B1s = (float*)((char*)d_ws + 73728);
    unsigned char* BT = (unsigned char*)d_ws + 75264;
    u32* cw = (u32*)((char*)d_ws + 2483712);

    if (wsW)
        hipLaunchKernelGGL(prep_weights, dim3(38), dim3(256), 0, stream,
                           w1, w2, lng, lnb, b1, W1L, W2L, B1s);
    if (wsBT)
        hipLaunchKernelGGL(prep_bt, dim3(1176), dim3(256), 0, stream, dww, BT);

    dim3 g1(64, 96, 2), blk(256);
    if (wsCW)
        hipLaunchKernelGGL((dwconvM<0>), g1, blk, 0, stream, x, BT, dwb, (u16*)cw, (u16*)d_out);
    else if (wsBT)
        hipLaunchKernelGGL((dwconvM<1>), g1, blk, 0, stream, x, BT, dwb, (u16*)cw, (u16*)d_out);
    else
        hipLaunchKernelGGL((dwconvA<1>), g1, blk, 0, stream, x, dww, dwb, cw, (u16*)d_out);

    dim3 g2(4096), blk2(256);
    if (wsCW)
        hipLaunchKernelGGL((mlp3<0, 0>), g2, blk2, 0, stream, (const void*)cw,
                           W1L, W2L, B1s, w1, w2, lng, lnb, b1, b2, gam, x, out);
    else if (wsW)
        hipLaunchKernelGGL((mlp3<1, 0>), g2, blk2, 0, stream, (const void*)d_out,
                           W1L, W2L, B1s, w1, w2, lng, lnb, b1, b2, gam, x, out);
    else
        hipLaunchKernelGGL((mlp3<1, 1>), g2, blk2, 0, stream, (const void*)d_out,
                           W1L, W2L, B1s, w1, w2, lng, lnb, b1, b2, gam, x, out);
}